// Round 19
// baseline (344.036 us; speedup 1.0000x reference)
//
#include <hip/hip_runtime.h>
#include <hip/hip_bf16.h>

typedef __bf16 bf16x8 __attribute__((ext_vector_type(8)));
typedef __bf16 bf16x4 __attribute__((ext_vector_type(4)));
typedef float  f32x4  __attribute__((ext_vector_type(4)));
typedef unsigned int u32;

#define HW_   3136            // 56*56
#define NPIX  200704          // 64*56*56
#define GI_ELEMS 25690112     // NPIX*128

// ---- workspace byte offsets ----
#define GOT_OFF   0u           // goT bf16 [co][pix]            51,380,224
#define RAW_OFF   51380224u    // raw fp32                          589,824
#define BIASA_OFF 51970048u    // bias accum                            512
#define STDKF_OFF 51970560u    // stdkF bf16                        294,912
#define GUARD_OFF 52265472u    // zero guard (gradin zsrc)              256
#define ZB_OFF    52265728u    // zero strip for B-pad lanes          6,272
#define ZA_OFF    52272000u    // zero strip for A-pad lanes          7,168
#define X_OFF     52279168u    // goB (51,380,224) then inT (60,817,408)

__device__ __forceinline__ f32x4 mfma16(bf16x8 a, bf16x8 b, f32x4 c){
  return __builtin_amdgcn_mfma_f32_16x16x32_bf16(a, b, c, 0, 0, 0);
}

__device__ __forceinline__ void async16(const void* g, __bf16* l){
  __builtin_amdgcn_global_load_lds(
      (const __attribute__((address_space(1))) void*)g,
      (__attribute__((address_space(3))) void*)l, 16, 0, 0);
}

// ---------------- std_kernels fp32 -> fragment-linear bf16 ----------------
__global__ __launch_bounds__(256) void k_prep(const float* __restrict__ s, __bf16* __restrict__ d){
  const int g = blockIdx.x*256 + threadIdx.x;   // 0..18431
  const int l = g & 63;
  const int j = (g >> 6) & 7;
  const int kc = (g >> 9) & 3;
  const int tap = g >> 11;
  const int ci = j*16 + (l & 15);
  const int co0 = kc*32 + (l >> 4)*8;
  const float* src = s + ((size_t)(tap*128 + ci))*128 + co0;
  f32x4 x0 = *(const f32x4*)src;
  f32x4 x1 = *(const f32x4*)(src + 4);
  bf16x8 y;
  #pragma unroll
  for (int e=0;e<4;e++){ y[e] = (__bf16)x0[e]; y[e+4] = (__bf16)x1[e]; }
  *(bf16x8*)(d + (size_t)g*8) = y;
}

// ---------------- go -> goT (bf16 [co][pix]) + goB (bf16 NHWC) + bias ----------------
__global__ __launch_bounds__(256) void k_goT(const float* __restrict__ go,
                                             __bf16* __restrict__ goT,
                                             __bf16* __restrict__ goB,
                                             float* __restrict__ biasA){
  __shared__ __bf16 T[64][130];
  __shared__ float biasS[128];
  const int t = threadIdx.x;
  const size_t p0 = (size_t)blockIdx.x*64;
  if (t < 128) biasS[t] = 0.f;
  __syncthreads();
  float bs[4] = {0.f,0.f,0.f,0.f};
  const int co0 = (t*4) & 127;
  #pragma unroll
  for (int i=0;i<8;i++){
    const int flat = (i*256+t)*4;
    const int px = flat >> 7, co = flat & 127;
    f32x4 x = *(const f32x4*)(go + p0*128 + flat);
    bf16x4 y;
    #pragma unroll
    for (int e=0;e<4;e++){ y[e] = (__bf16)x[e]; bs[e] += x[e]; }
    *(bf16x4*)&T[px][co] = y;
    *(bf16x4*)(goB + p0*128 + flat) = y;
  }
  #pragma unroll
  for (int e=0;e<4;e++) atomicAdd(&biasS[co0+e], bs[e]);
  __syncthreads();
  #pragma unroll
  for (int j=0;j<2;j++){
    const int task = j*256 + t;
    const int co = task >> 2, q = task & 3;
    bf16x8 v0, v1;
    #pragma unroll
    for (int k=0;k<8;k++) v0[k] = T[q*16+k][co];
    #pragma unroll
    for (int k=0;k<8;k++) v1[k] = T[q*16+8+k][co];
    __bf16* d = goT + (size_t)co*NPIX + p0 + q*16;
    *(bf16x8*)d = v0; *(bf16x8*)(d+8) = v1;
  }
  if (t < 128) atomicAdd(&biasA[t], biasS[t]);
}

// ---------------- inputs -> inTpad interior + pad-zeroing (fused padz) ----------------
__global__ __launch_bounds__(256) void k_inT(const float* __restrict__ inp,
                                             __bf16* __restrict__ inT){
  __shared__ __bf16 T[64][130];
  const int t = threadIdx.x;
  const size_t p0 = (size_t)blockIdx.x*64;

  if (blockIdx.x < 2304){
    const int g = blockIdx.x*256 + t;   // 0..589823
    const int pair = g / 72, k = g - pair*72;
    __bf16* base = inT + (size_t)pair*3712;
    int off;
    if (k < 8)       off = k*8;                   // row 0
    else if (k < 16) off = 57*64 + (k-8)*8;       // row 57
    else             off = (k-15)*64 + 56;        // rows 1..56, cols 56..63
    bf16x8 z = {};
    *(bf16x8*)(base + off) = z;
  }

  #pragma unroll
  for (int i=0;i<8;i++){
    const int flat = (i*256+t)*4;
    const int px = flat >> 7, ci = flat & 127;
    f32x4 x = *(const f32x4*)(inp + p0*128 + flat);
    bf16x4 y;
    #pragma unroll
    for (int e=0;e<4;e++) y[e] = (__bf16)x[e];
    *(bf16x4*)&T[px][ci] = y;
  }
  __syncthreads();
  #pragma unroll
  for (int j=0;j<4;j++){
    const int task = j*256 + t;
    const int ci = task >> 3, ch = task & 7;
    const int p = (int)p0 + ch*8;
    const int b = p / HW_; const int r = p - b*HW_;
    const int h = r / 56;  const int w = r - h*56;
    bf16x8 v;
    #pragma unroll
    for (int k=0;k<8;k++) v[k] = T[ch*8+k][ci];
    *(bf16x8*)(inT + (((size_t)(ci*64+b))*58 + (h+1))*64 + w) = v;
  }
}

// ---------------- grad_in v10: gradin9 shell + 2-deep B-prefetch (uncapped regs) ----------------
// Block = 224 px (4 rows) x 128 ci; wave = 112 px x 64 ci. LDS 44,544 B. (256,1): cap 256.
// Bf[2][4] rotation: issue (tap,kc)+1's 4 global L2 stdkF loads before current MFMAs.
// Flat fully-unrolled it-loop -> all Bf indices compile-time (rule #20). ~197 VGPR < 256.
#define LOADB(dst, tp, kg)                                                     \
  _Pragma("unroll")                                                            \
  for (int j=0;j<4;++j)                                                        \
    dst[j] = *(const bf16x8*)(stdkF + ((size_t)((((tp)*4 + (kg))*8 + j0 + j)*64 + l))*8);

__global__ __launch_bounds__(256, 1) void k_gradin10(const __bf16* __restrict__ goB,
                                                     const __bf16* __restrict__ stdkF,
                                                     const __bf16* __restrict__ zsrc,
                                                     float* __restrict__ out){
  __shared__ char LDS[44544];
  const int t = threadIdx.x;
  const int wv = t >> 6, l = t & 63, lr = l & 15, lg = l >> 4;
  const int b = blockIdx.x, h0 = blockIdx.y*4;
  const int j0 = (wv & 1)*4;            // ci half: j-groups [j0, j0+4)
  const int pxg = (wv >> 1)*112;        // pixel group (0 or 112)

  int sb[7];
  #pragma unroll
  for (int tile=0; tile<7; ++tile){
    const int p = pxg + tile*16 + lr;   // 0..223
    const int ro = p / 56; const int w = p - ro*56;
    sb[tile] = (ro + 2)*58 + (w + 2);
  }

  f32x4 acc[7][4];
  #pragma unroll
  for (int i=0;i<7;i++){
    #pragma unroll
    for (int j=0;j<4;j++){
      #pragma unroll
      for (int r=0;r<4;r++) acc[i][j][r] = 0.f;
    }
  }

  for (int c=0; c<2; ++c){
    // ---- stage this co-half: 2784 16B chunks (6 rows x 58 wp x 8 chunks) ----
    #pragma unroll
    for (int it=0; it<11; ++it){
      const int qb = it*256 + wv*64;
      const u32 q = (u32)(qb + l);
      if (q < 2784u){
        const u32 r = q / 464u;
        const u32 rem = q - r*464u;
        const u32 wp = rem >> 3;
        const u32 cl = rem & 7u;
        const int h = h0 - 1 + (int)r;
        const u32 s = r*58u + wp;
        const u32 csrc = cl ^ (s & 7u);
        const bool valid = (h >= 0) & (h < 56) & (wp >= 1u) & (wp <= 56u);
        const __bf16* src = valid
          ? goB + ((size_t)((b*HW_) + h*56 + ((int)wp - 1))*128 + c*64 + csrc*8)
          : zsrc;
        async16(src, (__bf16*)(LDS + qb*16));
      }
    }
    __syncthreads();

    bf16x8 Bf[2][4];
    LOADB(Bf[0], 0, c*2)
    #pragma unroll
    for (int it=0; it<18; ++it){
      const int tap = it >> 1, kc = it & 1;
      if (it < 17){
        const int nit = it + 1;
        LOADB(Bf[nit & 1], nit >> 1, c*2 + (nit & 1))
      }
      const int u = tap/3;
      const int soff = u*58 + (tap - u*3);
      bf16x8 Af[7];
      #pragma unroll
      for (int tile=0;tile<7;++tile){
        const int s = sb[tile] - soff;
        const int byte = (s << 7) | (((kc*4 + lg) ^ (s & 7)) << 4);
        Af[tile] = *(const bf16x8*)(LDS + byte);
      }
      #pragma unroll
      for (int tile=0;tile<7;++tile){
        #pragma unroll
        for (int j=0;j<4;++j)
          acc[tile][j] = mfma16(Af[tile], Bf[it & 1][j], acc[tile][j]);
      }
    }
    __syncthreads();
  }

  float* o = out + ((size_t)b*HW_ + (size_t)h0*56 + pxg)*128;
  #pragma unroll
  for (int tile=0;tile<7;++tile){
    #pragma unroll
    for (int j=0;j<4;++j){
      #pragma unroll
      for (int r=0;r<4;++r)
        o[(size_t)(tile*16 + 4*lg + r)*128 + (j0 + j)*16 + lr] = acc[tile][j][r];
    }
  }
}

// ---------------- grad_wt_raw v9 (BEST, 101.8us): dbuf 112-px chunks, 2 blocks/CU ----------------
// LDS elem map: B0[0,15360) B1[15360,30720) G0[30720,30728) A0[30728,34952)
//               G1[34952,34968) A1[34968,39192) G2[39192,39208)  = 78,416 B
#define KSTEP9(ks)                                                             \
{                                                                              \
  const int pl = (ks)*32 + lg*8;                                               \
  const int q  = (ks)*4 + lg;                                                  \
  const int hl = q / 7;                                                        \
  const int w0 = pl - hl*56;                                                   \
  const int plc = ((ks)==3 && lg==3) ? 112 : pl;                               \
  bf16x8 b0 = *(const bf16x8*)&Bb[(wco + lr)*120 + plc];                       \
  bf16x8 b1 = *(const bf16x8*)&Bb[(wco + 16 + lr)*120 + plc];                  \
  const __bf16* abase = &Ab[lr*264 + hl*64 + w0];                              \
  _Pragma("unroll")                                                            \
  for (int u=0; u<3; ++u){                                                     \
    const __bf16* ap = abase + u*64;                                           \
    union { bf16x8 v; u32 d[4]; } vp, va, vn, a0, a2;                          \
    vp.v = *(const bf16x8*)(ap - 8);                                           \
    va.v = *(const bf16x8*)ap;                                                 \
    vn.v = *(const bf16x8*)(ap + 8);                                           \
    if ((ks)==3 && lg >= 2){                                                   \
      vp.d[0]=0u; vp.d[1]=0u; vp.d[2]=0u; vp.d[3]=0u;                          \
      va.d[0]=0u; va.d[1]=0u; va.d[2]=0u; va.d[3]=0u;                          \
      vn.d[0]=0u; vn.d[1]=0u; vn.d[2]=0u; vn.d[3]=0u;                          \
    }                                                                          \
    a0.d[0] = (va.d[0] << 16) | (vp.d[3] >> 16);                               \
    a0.d[1] = (va.d[1] << 16) | (va.d[0] >> 16);                               \
    a0.d[2] = (va.d[2] << 16) | (va.d[1] >> 16);                               \
    a0.d[3] = (va.d[3] << 16) | (va.d[2] >> 16);                               \
    a2.d[0] = (va.d[0] >> 16) | (va.d[1] << 16);                               \
    a2.d[1] = (va.d[1] >> 16) | (va.d[2] << 16);                               \
    a2.d[2] = (va.d[2] >> 16) | (va.d[3] << 16);                               \
    a2.d[3] = (va.d[3] >> 16) | (vn.d[0] << 16);                               \
    acc[u*3+0][0] = mfma16(a0.v, b0, acc[u*3+0][0]);                           \
    acc[u*3+0][1] = mfma16(a0.v, b1, acc[u*3+0][1]);                           \
    acc[u*3+1][0] = mfma16(va.v, b0, acc[u*3+1][0]);                           \
    acc[u*3+1][1] = mfma16(va.v, b1, acc[u*3+1][1]);                           \
    acc[u*3+2][0] = mfma16(a2.v, b0, acc[u*3+2][0]);                           \
    acc[u*3+2][1] = mfma16(a2.v, b1, acc[u*3+2][1]);                           \
  }                                                                            \
}

__global__ __launch_bounds__(256, 2) void k_gradwt9(const char* __restrict__ ws,
                                                    float* __restrict__ raw){
  __shared__ __bf16 LDS[39208];
  const int t = threadIdx.x;
  const int w = t >> 6, l = t & 63, lr = l & 15, lg = l >> 4;
  const int b = blockIdx.x, ci0 = blockIdx.y*16;
  const int wco = w*32;

  if (t < 40){
    const int idx = (t < 8) ? (30720 + t) : ((t < 24) ? (34952 + t - 8) : (39192 + t - 24));
    LDS[idx] = (__bf16)0.f;
  }

  u32 boff[8];
  #pragma unroll
  for (int i=0;i<8;i++){
    const int chunk = i*256 + t;
    if (chunk < 1920){
      const int co = chunk / 15, part = chunk - co*15;
      boff[i] = (part < 14)
        ? (GOT_OFF + (u32)(co*NPIX + b*HW_ + part*8)*2u)
        : ZB_OFF;
    } else boff[i] = ZB_OFF;
  }
  u32 aoff[3];
  #pragma unroll
  for (int i=0;i<3;i++){
    const int chunk = i*256 + t;
    if (chunk < 528){
      const int ci = chunk / 33, r = chunk - ci*33;
      aoff[i] = (r < 32)
        ? (X_OFF + (u32)((((ci0+ci)*64 + b)*58 + (r>>3))*64 + (r&7)*8)*2u)
        : ZA_OFF;
    } else aoff[i] = ZA_OFF;
  }

  f32x4 acc[9][2];
  #pragma unroll
  for (int tp=0;tp<9;tp++){
    #pragma unroll
    for (int j=0;j<2;j++){
      #pragma unroll
      for (int r=0;r<4;r++) acc[tp][j][r] = 0.f;
    }
  }

  #pragma unroll
  for (int i=0;i<8;i++){
    const int chunk = i*256 + t;
    if (chunk < 1920){ async16(ws + boff[i], LDS + chunk*8); boff[i] += 224u; }
  }
  #pragma unroll
  for (int i=0;i<3;i++){
    const int chunk = i*256 + t;
    if (chunk < 528){ async16(ws + aoff[i], LDS + 30728 + chunk*8); aoff[i] += 256u; }
  }
  __syncthreads();

  for (int c=0; c<28; ++c){
    const int cur = c & 1;
    if (c < 27){
      __bf16* dB = LDS + ((cur ^ 1) ? 15360 : 0);
      __bf16* dA = LDS + ((cur ^ 1) ? 34968 : 30728);
      #pragma unroll
      for (int i=0;i<8;i++){
        const int chunk = i*256 + t;
        if (chunk < 1920){ async16(ws + boff[i], dB + chunk*8); boff[i] += 224u; }
      }
      #pragma unroll
      for (int i=0;i<3;i++){
        const int chunk = i*256 + t;
        if (chunk < 528){ async16(ws + aoff[i], dA + chunk*8); aoff[i] += 256u; }
      }
    }
    const __bf16* Bb = LDS + (cur ? 15360 : 0);
    const __bf16* Ab = LDS + (cur ? 34968 : 30728);
    KSTEP9(0) KSTEP9(1) KSTEP9(2) KSTEP9(3)
    __syncthreads();
  }

  #pragma unroll
  for (int tp=0;tp<9;tp++){
    #pragma unroll
    for (int j=0;j<2;j++){
      #pragma unroll
      for (int r=0;r<4;r++)
        atomicAdd(&raw[(size_t)(tp*128 + ci0 + 4*lg + r)*128 + wco + j*16 + lr],
                  acc[tp][j][r]);
    }
  }
}

// ---------------- weight-standardization backward chain + bias/gain ----------------
__global__ __launch_bounds__(128) void k_std(const float* __restrict__ raw,
      const float* __restrict__ kern, const float* __restrict__ gain,
      const float* __restrict__ bmap, const float* __restrict__ biasA,
      float* __restrict__ out_wt, float* __restrict__ out_bias, float* __restrict__ out_gain){
  const int co = blockIdx.x, t = threadIdx.x;
  float kv[9], gv[9];
  float s1=0.f, s2=0.f, sg=0.f, sgk=0.f;
  #pragma unroll
  for (int i=0;i<9;i++){
    const int m = t + i*128;
    const float k_ = kern[(size_t)m*128 + co];
    const float g_ = raw [(size_t)m*128 + co];
    kv[i]=k_; gv[i]=g_;
    s1 += k_; s2 += k_*k_; sg += g_; sgk += g_*k_;
  }
  __shared__ float red[4][128];
  red[0][t]=s1; red[1][t]=s2; red[2][t]=sg; red[3][t]=sgk;
  __syncthreads();
  for (int off=64; off>0; off>>=1){
    if (t < off){
      red[0][t]+=red[0][t+off]; red[1][t]+=red[1][t+off];
      red[2][t]+=red[2][t+off]; red[3][t]+=red[3][t+off];
    }
    __syncthreads();
  }
  const float N = 1152.f;
  const float S1=red[0][0], S2=red[1][0], Sg=red[2][0], Sgk=red[3][0];
  const float mu = S1/N;
  const float var = S2/N - mu*mu;
  const float mvar = N*var;
  const float maxvar = fmaxf(mvar, 1e-4f);
  const float sqrtvar = sqrtf(maxvar);
  const float ivar = 1.f/sqrtvar;
  const float g = gain[co];
  const float givar = g*ivar;
  const float dgivar = Sgk - mu*Sg;
  const float divar = dgivar*g;
  const float dsqrtvar = -divar/maxvar;
  const float dmaxvar = 0.5f*dsqrtvar/sqrtvar;
  const float dsq = bmap[co]*dmaxvar;
  const float dmu = -(givar*Sg + 2.f*dsq*(S1 - N*mu));
  const float dmuN = dmu*(1.f/N);
  #pragma unroll
  for (int i=0;i<9;i++){
    const int m = t + i*128;
    out_wt[(size_t)m*128 + co] = gv[i]*givar + 2.f*(kv[i]-mu)*dsq + dmuN;
  }
  if (t == 0){ out_gain[co] = dgivar*ivar; out_bias[co] = biasA[co]; }
}

extern "C" void kernel_launch(void* const* d_in, const int* in_sizes, int n_in,
                              void* d_out, int out_size, void* d_ws, size_t ws_size,
                              hipStream_t stream){
  const float* go   = (const float*)d_in[0];
  const float* inp  = (const float*)d_in[1];
  const float* kern = (const float*)d_in[2];
  const float* stdk = (const float*)d_in[3];
  const float* gain = (const float*)d_in[4];
  const float* bmap = (const float*)d_in[5];

  char* ws = (char*)d_ws;
  __bf16* goT   = (__bf16*)(ws + GOT_OFF);
  float*  raw   = (float*) (ws + RAW_OFF);
  float*  biasA = (float*) (ws + BIASA_OFF);
  __bf16* stdkF = (__bf16*)(ws + STDKF_OFF);
  char*   guard =           ws + GUARD_OFF;
  __bf16* goB   = (__bf16*)(ws + X_OFF);
  __bf16* inT   = (__bf16*)(ws + X_OFF);   // overlays goB after gradin10

  hipMemsetAsync(ws + RAW_OFF,   0, 589824 + 512, stream);      // raw + biasA
  hipMemsetAsync(ws + GUARD_OFF, 0, 256 + 6272 + 7168, stream); // guard + ZB + ZA

  k_prep  <<<72, 256, 0, stream>>>(stdk, stdkF);
  k_goT   <<<3136, 256, 0, stream>>>(go, goT, goB, biasA);
  k_gradin10<<<dim3(64,14), 256, 0, stream>>>(goB, stdkF, (const __bf16*)guard, (float*)d_out);

  // inT overlays goB -> touch only after gradin10 consumed goB (padz fused into k_inT)
  k_inT   <<<3136, 256, 0, stream>>>(inp, inT);
  k_gradwt9<<<dim3(64,8), 256, 0, stream>>>((const char*)ws, raw);

  float* out = (float*)d_out;
  k_std<<<128, 128, 0, stream>>>(raw, kern, gain, bmap, biasA,
                                 out + GI_ELEMS,
                                 out + GI_ELEMS + 147456,
                                 out + GI_ELEMS + 147456 + 128);
}

// Round 20
// 296.998 us; speedup vs baseline: 1.1584x; 1.1584x over previous
//
#include <hip/hip_runtime.h>
#include <hip/hip_bf16.h>

typedef __bf16 bf16x8 __attribute__((ext_vector_type(8)));
typedef __bf16 bf16x4 __attribute__((ext_vector_type(4)));
typedef float  f32x4  __attribute__((ext_vector_type(4)));
typedef unsigned int u32;

#define HW_   3136            // 56*56
#define NPIX  200704          // 64*56*56
#define GI_ELEMS 25690112     // NPIX*128

// ---- workspace byte offsets ----
#define GOT_OFF   0u           // goT bf16 [co][pix]            51,380,224
#define RAW_OFF   51380224u    // raw fp32                          589,824
#define BIASA_OFF 51970048u    // bias accum                            512
#define STDKF_OFF 51970560u    // stdkF bf16                        294,912
#define GUARD_OFF 52265472u    // zero guard (gradin zsrc)              256
#define ZB_OFF    52265728u    // zero strip for B-pad lanes          6,272
#define ZA_OFF    52272000u    // zero strip for A-pad lanes          7,168
#define X_OFF     52279168u    // goB (51,380,224) then inT (60,817,408)

__device__ __forceinline__ f32x4 mfma16(bf16x8 a, bf16x8 b, f32x4 c){
  return __builtin_amdgcn_mfma_f32_16x16x32_bf16(a, b, c, 0, 0, 0);
}

__device__ __forceinline__ void async16(const void* g, __bf16* l){
  __builtin_amdgcn_global_load_lds(
      (const __attribute__((address_space(1))) void*)g,
      (__attribute__((address_space(3))) void*)l, 16, 0, 0);
}

// ---------------- std_kernels fp32 -> fragment-linear bf16 ----------------
__global__ __launch_bounds__(256) void k_prep(const float* __restrict__ s, __bf16* __restrict__ d){
  const int g = blockIdx.x*256 + threadIdx.x;   // 0..18431
  const int l = g & 63;
  const int j = (g >> 6) & 7;
  const int kc = (g >> 9) & 3;
  const int tap = g >> 11;
  const int ci = j*16 + (l & 15);
  const int co0 = kc*32 + (l >> 4)*8;
  const float* src = s + ((size_t)(tap*128 + ci))*128 + co0;
  f32x4 x0 = *(const f32x4*)src;
  f32x4 x1 = *(const f32x4*)(src + 4);
  bf16x8 y;
  #pragma unroll
  for (int e=0;e<4;e++){ y[e] = (__bf16)x0[e]; y[e+4] = (__bf16)x1[e]; }
  *(bf16x8*)(d + (size_t)g*8) = y;
}

// ---------------- go -> goT (bf16 [co][pix]) + goB (bf16 NHWC) + bias ----------------
__global__ __launch_bounds__(256) void k_goT(const float* __restrict__ go,
                                             __bf16* __restrict__ goT,
                                             __bf16* __restrict__ goB,
                                             float* __restrict__ biasA){
  __shared__ __bf16 T[64][130];
  __shared__ float biasS[128];
  const int t = threadIdx.x;
  const size_t p0 = (size_t)blockIdx.x*64;
  if (t < 128) biasS[t] = 0.f;
  __syncthreads();
  float bs[4] = {0.f,0.f,0.f,0.f};
  const int co0 = (t*4) & 127;
  #pragma unroll
  for (int i=0;i<8;i++){
    const int flat = (i*256+t)*4;
    const int px = flat >> 7, co = flat & 127;
    f32x4 x = *(const f32x4*)(go + p0*128 + flat);
    bf16x4 y;
    #pragma unroll
    for (int e=0;e<4;e++){ y[e] = (__bf16)x[e]; bs[e] += x[e]; }
    *(bf16x4*)&T[px][co] = y;
    *(bf16x4*)(goB + p0*128 + flat) = y;
  }
  #pragma unroll
  for (int e=0;e<4;e++) atomicAdd(&biasS[co0+e], bs[e]);
  __syncthreads();
  #pragma unroll
  for (int j=0;j<2;j++){
    const int task = j*256 + t;
    const int co = task >> 2, q = task & 3;
    bf16x8 v0, v1;
    #pragma unroll
    for (int k=0;k<8;k++) v0[k] = T[q*16+k][co];
    #pragma unroll
    for (int k=0;k<8;k++) v1[k] = T[q*16+8+k][co];
    __bf16* d = goT + (size_t)co*NPIX + p0 + q*16;
    *(bf16x8*)d = v0; *(bf16x8*)(d+8) = v1;
  }
  if (t < 128) atomicAdd(&biasA[t], biasS[t]);
}

// ---------------- inputs -> inTpad interior + pad-zeroing (fused padz) ----------------
__global__ __launch_bounds__(256) void k_inT(const float* __restrict__ inp,
                                             __bf16* __restrict__ inT){
  __shared__ __bf16 T[64][130];
  const int t = threadIdx.x;
  const size_t p0 = (size_t)blockIdx.x*64;

  if (blockIdx.x < 2304){
    const int g = blockIdx.x*256 + t;   // 0..589823
    const int pair = g / 72, k = g - pair*72;
    __bf16* base = inT + (size_t)pair*3712;
    int off;
    if (k < 8)       off = k*8;                   // row 0
    else if (k < 16) off = 57*64 + (k-8)*8;       // row 57
    else             off = (k-15)*64 + 56;        // rows 1..56, cols 56..63
    bf16x8 z = {};
    *(bf16x8*)(base + off) = z;
  }

  #pragma unroll
  for (int i=0;i<8;i++){
    const int flat = (i*256+t)*4;
    const int px = flat >> 7, ci = flat & 127;
    f32x4 x = *(const f32x4*)(inp + p0*128 + flat);
    bf16x4 y;
    #pragma unroll
    for (int e=0;e<4;e++) y[e] = (__bf16)x[e];
    *(bf16x4*)&T[px][ci] = y;
  }
  __syncthreads();
  #pragma unroll
  for (int j=0;j<4;j++){
    const int task = j*256 + t;
    const int ci = task >> 3, ch = task & 7;
    const int p = (int)p0 + ch*8;
    const int b = p / HW_; const int r = p - b*HW_;
    const int h = r / 56;  const int w = r - h*56;
    bf16x8 v;
    #pragma unroll
    for (int k=0;k<8;k++) v[k] = T[ch*8+k][ci];
    *(bf16x8*)(inT + (((size_t)(ci*64+b))*58 + (h+1))*64 + w) = v;
  }
}

// ---------------- grad_in v9 (BEST): 256-thr/4-wave blocks, uncapped allocator ----------------
// Block = 224 px (4 rows) x 128 ci; wave = 112 px x 64 ci. LDS: 44,544 B. (256,1): cap 256,
// compiler ~165-170 VGPR, no spill; 2-3 blocks/CU from actual register use.
__global__ __launch_bounds__(256, 1) void k_gradin9(const __bf16* __restrict__ goB,
                                                    const __bf16* __restrict__ stdkF,
                                                    const __bf16* __restrict__ zsrc,
                                                    float* __restrict__ out){
  __shared__ char LDS[44544];
  const int t = threadIdx.x;
  const int wv = t >> 6, l = t & 63, lr = l & 15, lg = l >> 4;
  const int b = blockIdx.x, h0 = blockIdx.y*4;
  const int j0 = (wv & 1)*4;            // ci half: j-groups [j0, j0+4)
  const int pxg = (wv >> 1)*112;        // pixel group (0 or 112; 224 px total)

  int sb[7];
  #pragma unroll
  for (int tile=0; tile<7; ++tile){
    const int p = pxg + tile*16 + lr;   // 0..223
    const int ro = p / 56; const int w = p - ro*56;
    sb[tile] = (ro + 2)*58 + (w + 2);
  }

  f32x4 acc[7][4];
  #pragma unroll
  for (int i=0;i<7;i++){
    #pragma unroll
    for (int j=0;j<4;j++){
      #pragma unroll
      for (int r=0;r<4;r++) acc[i][j][r] = 0.f;
    }
  }

  for (int c=0; c<2; ++c){
    // ---- stage this co-half: 2784 16B chunks (6 rows x 58 wp x 8 chunks) ----
    #pragma unroll
    for (int it=0; it<11; ++it){
      const int qb = it*256 + wv*64;    // wave-uniform LDS base
      const u32 q = (u32)(qb + l);
      if (q < 2784u){
        const u32 r = q / 464u;         // 0..5 -> input row h0-1+r
        const u32 rem = q - r*464u;
        const u32 wp = rem >> 3;
        const u32 cl = rem & 7u;
        const int h = h0 - 1 + (int)r;
        const u32 s = r*58u + wp;
        const u32 csrc = cl ^ (s & 7u);
        const bool valid = (h >= 0) & (h < 56) & (wp >= 1u) & (wp <= 56u);
        const __bf16* src = valid
          ? goB + ((size_t)((b*HW_) + h*56 + ((int)wp - 1))*128 + c*64 + csrc*8)
          : zsrc;
        async16(src, (__bf16*)(LDS + qb*16));
      }
    }
    __syncthreads();

    for (int tap=0; tap<9; ++tap){
      const int u = tap/3;
      const int soff = u*58 + (tap - u*3);
      #pragma unroll
      for (int kc=0; kc<2; ++kc){
        const int kcg = c*2 + kc;
        bf16x8 Bf[4];
        #pragma unroll
        for (int j=0;j<4;++j)
          Bf[j] = *(const bf16x8*)(stdkF + ((size_t)(((tap*4 + kcg)*8 + j0 + j)*64 + l))*8);
        bf16x8 Af[7];
        #pragma unroll
        for (int tile=0;tile<7;++tile){
          const int s = sb[tile] - soff;
          const int byte = (s << 7) | (((kc*4 + lg) ^ (s & 7)) << 4);
          Af[tile] = *(const bf16x8*)(LDS + byte);
        }
        #pragma unroll
        for (int tile=0;tile<7;++tile){
          #pragma unroll
          for (int j=0;j<4;++j)
            acc[tile][j] = mfma16(Af[tile], Bf[j], acc[tile][j]);
        }
      }
    }
    __syncthreads();
  }

  float* o = out + ((size_t)b*HW_ + (size_t)h0*56 + pxg)*128;
  #pragma unroll
  for (int tile=0;tile<7;++tile){
    #pragma unroll
    for (int j=0;j<4;++j){
      #pragma unroll
      for (int r=0;r<4;++r)
        o[(size_t)(tile*16 + 4*lg + r)*128 + (j0 + j)*16 + lr] = acc[tile][j][r];
    }
  }
}

// ---------------- grad_wt_raw v9 (BEST, 101.8us): dbuf 112-px chunks, 2 blocks/CU ----------------
// LDS elem map: B0[0,15360) B1[15360,30720) G0[30720,30728) A0[30728,34952)
//               G1[34952,34968) A1[34968,39192) G2[39192,39208)  = 78,416 B
#define KSTEP9(ks)                                                             \
{                                                                              \
  const int pl = (ks)*32 + lg*8;                                               \
  const int q  = (ks)*4 + lg;                                                  \
  const int hl = q / 7;                                                        \
  const int w0 = pl - hl*56;                                                   \
  const int plc = ((ks)==3 && lg==3) ? 112 : pl;                               \
  bf16x8 b0 = *(const bf16x8*)&Bb[(wco + lr)*120 + plc];                       \
  bf16x8 b1 = *(const bf16x8*)&Bb[(wco + 16 + lr)*120 + plc];                  \
  const __bf16* abase = &Ab[lr*264 + hl*64 + w0];                              \
  _Pragma("unroll")                                                            \
  for (int u=0; u<3; ++u){                                                     \
    const __bf16* ap = abase + u*64;                                           \
    union { bf16x8 v; u32 d[4]; } vp, va, vn, a0, a2;                          \
    vp.v = *(const bf16x8*)(ap - 8);                                           \
    va.v = *(const bf16x8*)ap;                                                 \
    vn.v = *(const bf16x8*)(ap + 8);                                           \
    if ((ks)==3 && lg >= 2){                                                   \
      vp.d[0]=0u; vp.d[1]=0u; vp.d[2]=0u; vp.d[3]=0u;                          \
      va.d[0]=0u; va.d[1]=0u; va.d[2]=0u; va.d[3]=0u;                          \
      vn.d[0]=0u; vn.d[1]=0u; vn.d[2]=0u; vn.d[3]=0u;                          \
    }                                                                          \
    a0.d[0] = (va.d[0] << 16) | (vp.d[3] >> 16);                               \
    a0.d[1] = (va.d[1] << 16) | (va.d[0] >> 16);                               \
    a0.d[2] = (va.d[2] << 16) | (va.d[1] >> 16);                               \
    a0.d[3] = (va.d[3] << 16) | (va.d[2] >> 16);                               \
    a2.d[0] = (va.d[0] >> 16) | (va.d[1] << 16);                               \
    a2.d[1] = (va.d[1] >> 16) | (va.d[2] << 16);                               \
    a2.d[2] = (va.d[2] >> 16) | (va.d[3] << 16);                               \
    a2.d[3] = (va.d[3] >> 16) | (vn.d[0] << 16);                               \
    acc[u*3+0][0] = mfma16(a0.v, b0, acc[u*3+0][0]);                           \
    acc[u*3+0][1] = mfma16(a0.v, b1, acc[u*3+0][1]);                           \
    acc[u*3+1][0] = mfma16(va.v, b0, acc[u*3+1][0]);                           \
    acc[u*3+1][1] = mfma16(va.v, b1, acc[u*3+1][1]);                           \
    acc[u*3+2][0] = mfma16(a2.v, b0, acc[u*3+2][0]);                           \
    acc[u*3+2][1] = mfma16(a2.v, b1, acc[u*3+2][1]);                           \
  }                                                                            \
}

__global__ __launch_bounds__(256, 2) void k_gradwt9(const char* __restrict__ ws,
                                                    float* __restrict__ raw){
  __shared__ __bf16 LDS[39208];
  const int t = threadIdx.x;
  const int w = t >> 6, l = t & 63, lr = l & 15, lg = l >> 4;
  const int b = blockIdx.x, ci0 = blockIdx.y*16;
  const int wco = w*32;

  if (t < 40){
    const int idx = (t < 8) ? (30720 + t) : ((t < 24) ? (34952 + t - 8) : (39192 + t - 24));
    LDS[idx] = (__bf16)0.f;
  }

  u32 boff[8];
  #pragma unroll
  for (int i=0;i<8;i++){
    const int chunk = i*256 + t;
    if (chunk < 1920){
      const int co = chunk / 15, part = chunk - co*15;
      boff[i] = (part < 14)
        ? (GOT_OFF + (u32)(co*NPIX + b*HW_ + part*8)*2u)
        : ZB_OFF;
    } else boff[i] = ZB_OFF;
  }
  u32 aoff[3];
  #pragma unroll
  for (int i=0;i<3;i++){
    const int chunk = i*256 + t;
    if (chunk < 528){
      const int ci = chunk / 33, r = chunk - ci*33;
      aoff[i] = (r < 32)
        ? (X_OFF + (u32)((((ci0+ci)*64 + b)*58 + (r>>3))*64 + (r&7)*8)*2u)
        : ZA_OFF;
    } else aoff[i] = ZA_OFF;
  }

  f32x4 acc[9][2];
  #pragma unroll
  for (int tp=0;tp<9;tp++){
    #pragma unroll
    for (int j=0;j<2;j++){
      #pragma unroll
      for (int r=0;r<4;r++) acc[tp][j][r] = 0.f;
    }
  }

  #pragma unroll
  for (int i=0;i<8;i++){
    const int chunk = i*256 + t;
    if (chunk < 1920){ async16(ws + boff[i], LDS + chunk*8); boff[i] += 224u; }
  }
  #pragma unroll
  for (int i=0;i<3;i++){
    const int chunk = i*256 + t;
    if (chunk < 528){ async16(ws + aoff[i], LDS + 30728 + chunk*8); aoff[i] += 256u; }
  }
  __syncthreads();

  for (int c=0; c<28; ++c){
    const int cur = c & 1;
    if (c < 27){
      __bf16* dB = LDS + ((cur ^ 1) ? 15360 : 0);
      __bf16* dA = LDS + ((cur ^ 1) ? 34968 : 30728);
      #pragma unroll
      for (int i=0;i<8;i++){
        const int chunk = i*256 + t;
        if (chunk < 1920){ async16(ws + boff[i], dB + chunk*8); boff[i] += 224u; }
      }
      #pragma unroll
      for (int i=0;i<3;i++){
        const int chunk = i*256 + t;
        if (chunk < 528){ async16(ws + aoff[i], dA + chunk*8); aoff[i] += 256u; }
      }
    }
    const __bf16* Bb = LDS + (cur ? 15360 : 0);
    const __bf16* Ab = LDS + (cur ? 34968 : 30728);
    KSTEP9(0) KSTEP9(1) KSTEP9(2) KSTEP9(3)
    __syncthreads();
  }

  #pragma unroll
  for (int tp=0;tp<9;tp++){
    #pragma unroll
    for (int j=0;j<2;j++){
      #pragma unroll
      for (int r=0;r<4;r++)
        atomicAdd(&raw[(size_t)(tp*128 + ci0 + 4*lg + r)*128 + wco + j*16 + lr],
                  acc[tp][j][r]);
    }
  }
}

// ---------------- weight-standardization backward chain + bias/gain ----------------
__global__ __launch_bounds__(128) void k_std(const float* __restrict__ raw,
      const float* __restrict__ kern, const float* __restrict__ gain,
      const float* __restrict__ bmap, const float* __restrict__ biasA,
      float* __restrict__ out_wt, float* __restrict__ out_bias, float* __restrict__ out_gain){
  const int co = blockIdx.x, t = threadIdx.x;
  float kv[9], gv[9];
  float s1=0.f, s2=0.f, sg=0.f, sgk=0.f;
  #pragma unroll
  for (int i=0;i<9;i++){
    const int m = t + i*128;
    const float k_ = kern[(size_t)m*128 + co];
    const float g_ = raw [(size_t)m*128 + co];
    kv[i]=k_; gv[i]=g_;
    s1 += k_; s2 += k_*k_; sg += g_; sgk += g_*k_;
  }
  __shared__ float red[4][128];
  red[0][t]=s1; red[1][t]=s2; red[2][t]=sg; red[3][t]=sgk;
  __syncthreads();
  for (int off=64; off>0; off>>=1){
    if (t < off){
      red[0][t]+=red[0][t+off]; red[1][t]+=red[1][t+off];
      red[2][t]+=red[2][t+off]; red[3][t]+=red[3][t+off];
    }
    __syncthreads();
  }
  const float N = 1152.f;
  const float S1=red[0][0], S2=red[1][0], Sg=red[2][0], Sgk=red[3][0];
  const float mu = S1/N;
  const float var = S2/N - mu*mu;
  const float mvar = N*var;
  const float maxvar = fmaxf(mvar, 1e-4f);
  const float sqrtvar = sqrtf(maxvar);
  const float ivar = 1.f/sqrtvar;
  const float g = gain[co];
  const float givar = g*ivar;
  const float dgivar = Sgk - mu*Sg;
  const float divar = dgivar*g;
  const float dsqrtvar = -divar/maxvar;
  const float dmaxvar = 0.5f*dsqrtvar/sqrtvar;
  const float dsq = bmap[co]*dmaxvar;
  const float dmu = -(givar*Sg + 2.f*dsq*(S1 - N*mu));
  const float dmuN = dmu*(1.f/N);
  #pragma unroll
  for (int i=0;i<9;i++){
    const int m = t + i*128;
    out_wt[(size_t)m*128 + co] = gv[i]*givar + 2.f*(kv[i]-mu)*dsq + dmuN;
  }
  if (t == 0){ out_gain[co] = dgivar*ivar; out_bias[co] = biasA[co]; }
}

extern "C" void kernel_launch(void* const* d_in, const int* in_sizes, int n_in,
                              void* d_out, int out_size, void* d_ws, size_t ws_size,
                              hipStream_t stream){
  const float* go   = (const float*)d_in[0];
  const float* inp  = (const float*)d_in[1];
  const float* kern = (const float*)d_in[2];
  const float* stdk = (const float*)d_in[3];
  const float* gain = (const float*)d_in[4];
  const float* bmap = (const float*)d_in[5];

  char* ws = (char*)d_ws;
  __bf16* goT   = (__bf16*)(ws + GOT_OFF);
  float*  raw   = (float*) (ws + RAW_OFF);
  float*  biasA = (float*) (ws + BIASA_OFF);
  __bf16* stdkF = (__bf16*)(ws + STDKF_OFF);
  char*   guard =           ws + GUARD_OFF;
  __bf16* goB   = (__bf16*)(ws + X_OFF);
  __bf16* inT   = (__bf16*)(ws + X_OFF);   // overlays goB after gradin9

  hipMemsetAsync(ws + RAW_OFF,   0, 589824 + 512, stream);      // raw + biasA
  hipMemsetAsync(ws + GUARD_OFF, 0, 256 + 6272 + 7168, stream); // guard + ZB + ZA

  k_prep  <<<72, 256, 0, stream>>>(stdk, stdkF);
  k_goT   <<<3136, 256, 0, stream>>>(go, goT, goB, biasA);
  k_gradin9<<<dim3(64,14), 256, 0, stream>>>(goB, stdkF, (const __bf16*)guard, (float*)d_out);

  // inT overlays goB -> touch only after gradin9 consumed goB (padz fused into k_inT)
  k_inT   <<<3136, 256, 0, stream>>>(inp, inT);
  k_gradwt9<<<dim3(64,8), 256, 0, stream>>>((const char*)ws, raw);

  float* out = (float*)d_out;
  k_std<<<128, 128, 0, stream>>>(raw, kern, gain, bmap, biasA,
                                 out + GI_ELEMS,
                                 out + GI_ELEMS + 147456,
                                 out + GI_ELEMS + 147456 + 128);
}